// Round 15
// baseline (12094.306 us; speedup 1.0000x reference)
//
#include <hip/hip_runtime.h>
#include <hip/hip_bf16.h>
#include <cstddef>
#include <cstdint>

#define PP 32
#define BB 64
#define TT 100
#define WW 50
#define EE 64
#define HH 256
// ALPHA = 0.5, (1-ALPHA)/P = 0.015625

typedef float f4 __attribute__((ext_vector_type(4)));
typedef __attribute__((ext_vector_type(8))) short short8;   // 8 bf16
typedef __attribute__((ext_vector_type(4))) float f32x4;

__device__ __forceinline__ float sigm(float x) { return 1.0f / (1.0f + expf(-x)); }
__device__ __forceinline__ float splus(float x) {
    return fmaxf(x, 0.0f) + log1pf(expf(-fabsf(x)));
}
__device__ __forceinline__ unsigned short bfh(float x) {
    __hip_bfloat16 h = __float2bfloat16(x);           // RNE
    return *reinterpret_cast<unsigned short*>(&h);
}
__device__ __forceinline__ float bff(unsigned short u) {
    __hip_bfloat16 h; *reinterpret_cast<unsigned short*>(&h) = u;
    return __bfloat162float(h);
}

// ---------------------------------------------------------------------------
// Prologue A: emb[t][b][e] (fp32) = relu(prev_window[b,t,:] @ W_act + b_act)
// xobs[t*64+b] = emb . W_obs[256:320] + b_obs (fp32 exact)
// ---------------------------------------------------------------------------
__global__ __launch_bounds__(256) void k_emb(
    const float* __restrict__ pw, const float* __restrict__ w_act,
    const float* __restrict__ b_act, const float* __restrict__ w_obs,
    const float* __restrict__ b_obs,
    float* __restrict__ emb, float* __restrict__ xobs)
{
    int tid = threadIdx.x;
    int sub = tid >> 6;
    int e   = tid & 63;
    int bt  = blockIdx.x * 4 + sub;   // = b*100 + t
    int b = bt / TT, t = bt % TT;

    __shared__ float pws[4][WW + 2];
    if (e < WW) pws[sub][e] = pw[(size_t)bt * WW + e];
    __syncthreads();

    float acc = b_act[e];
    #pragma unroll 5
    for (int w = 0; w < WW; ++w) acc += pws[sub][w] * w_act[w * EE + e];
    float r = fmaxf(acc, 0.0f);
    emb[((size_t)t * BB + b) * EE + e] = r;

    float xv = r * w_obs[HH + e];
    #pragma unroll
    for (int d = 1; d < 64; d <<= 1) xv += __shfl_xor(xv, d);
    if (e == 0) xobs[t * BB + b] = xv + b_obs[0];
}

// ---------------------------------------------------------------------------
// Prologue A2: embW2[t][b][col] = sum_e emb[t,b,e]*W_ih[e,col]  (fp32 exact)
// grid (t 100 x cp 16) x 256 thr.
// ---------------------------------------------------------------------------
__global__ __launch_bounds__(256) void k_embW(
    const float* __restrict__ emb, const float* __restrict__ W_ih,
    float* __restrict__ embW2)
{
    int t  = blockIdx.x / 16;
    int cp = blockIdx.x - t * 16;
    int tid = threadIdx.x;

    __shared__ float le[64][65];   // [b][e]
    __shared__ float lw[64][80];   // [e][g*16+lh]

    {
        const f4* src = (const f4*)(emb + (size_t)t * 4096);
        for (int i = tid; i < 1024; i += 256) {
            f4 v = src[i];
            int b = i >> 4, e0 = (i & 15) * 4;
            le[b][e0 + 0] = v.x; le[b][e0 + 1] = v.y;
            le[b][e0 + 2] = v.z; le[b][e0 + 3] = v.w;
        }
        for (int i = tid; i < 5120; i += 256) {
            int e = i / 80, c = i - e * 80;
            int g = c >> 4, lh = c & 15;
            lw[e][c] = W_ih[(size_t)e * 1280 + g * 256 + cp * 16 + lh];
        }
    }
    __syncthreads();

    int lh = tid & 15, bq = tid >> 4;   // bq 0..15 (4 b's each)
    #pragma unroll
    for (int g = 0; g < 5; ++g) {
        float a0 = 0, a1 = 0, a2 = 0, a3 = 0;
        #pragma unroll
        for (int e = 0; e < 64; ++e) {
            float wv = lw[e][g * 16 + lh];
            a0 += le[bq * 4 + 0][e] * wv;
            a1 += le[bq * 4 + 1][e] * wv;
            a2 += le[bq * 4 + 2][e] * wv;
            a3 += le[bq * 4 + 3][e] * wv;
        }
        size_t base = ((size_t)t * 64) * 1280 + g * 256 + cp * 16 + lh;
        embW2[base + (size_t)(bq * 4 + 0) * 1280] = a0;
        embW2[base + (size_t)(bq * 4 + 1) * 1280] = a1;
        embW2[base + (size_t)(bq * 4 + 2) * 1280] = a2;
        embW2[base + (size_t)(bq * 4 + 3) * 1280] = a3;
    }
}

// ---------------------------------------------------------------------------
// Prologue B: pack W_hh into per-wave LINEAR streams, bf16 hi/lo.
// Index i = ((((w*8 + cs)*10 + cf)*2 + hl)*64 + lane)*8 + e   (655360 total)
//   ha = cf/5, g = cf%5, hf = 2w + ha
//   k = cs*32 + (lane>>4)*8 + e ; col = g*256 + hf*16 + (lane&15)
// Per (w, cs): 20 KB contiguous (exact consumption order).
// ---------------------------------------------------------------------------
__global__ __launch_bounds__(256) void k_packB2(
    const float* __restrict__ W_hh, unsigned short* __restrict__ Bpk2)
{
    int i = blockIdx.x * 256 + threadIdx.x;      // 655360
    int e    = i & 7;
    int r    = i >> 3;
    int lane = r & 63;  r >>= 6;
    int hl   = r & 1;   r >>= 1;
    int cf   = r % 10;  r /= 10;
    int cs   = r & 7;
    int w    = r >> 3;

    int ha = cf / 5, g = cf - ha * 5;
    int hf = 2 * w + ha;
    int k   = cs * 32 + (lane >> 4) * 8 + e;
    int col = g * 256 + hf * 16 + (lane & 15);
    float wv = W_hh[(size_t)k * 1280 + col];
    unsigned short uh = bfh(wv);
    Bpk2[i] = hl ? bfh(wv - bff(uh)) : uh;
}

// ---------------------------------------------------------------------------
// pf_all: ONE kernel, 32 blocks (2 batch columns each) x 512 thr (8 waves).
// Per block: h/c for 64 rows LDS-resident; per step: GEMM (M=64, N=1280,
// K=256, bf16 hi/lo 3-term + exact fp32 embW) -> LSTM -> dots ->
// block-local resample per b.  B read as per-wave linear streams.
// ---------------------------------------------------------------------------
__global__ __launch_bounds__(512, 2) void pf_all(
    const unsigned short* __restrict__ Bpk2,
    const float* __restrict__ embW2,
    const float* __restrict__ h0, const float* __restrict__ c0,
    const float* __restrict__ eps, const float* __restrict__ gumG,
    const float* __restrict__ xobs,
    const float* __restrict__ b_ih, const float* __restrict__ b_hh,
    const float* __restrict__ W_obs, const float* __restrict__ W_lab,
    const float* __restrict__ b_lab,
    float* __restrict__ y_out, float* __restrict__ pf_out)
{
    __shared__ unsigned short hhS[64 * 264];   // 33,792 B
    __shared__ unsigned short hlS[64 * 264];   // 33,792 B
    __shared__ float cS[64 * 264];             // 67,584 B
    __shared__ float gumS[2][32][33];          //  8,448 B
    __shared__ float wdp[8][64][2];            //  4,096 B
    __shared__ int   idxS[2][32];              //    256 B

    const int tid  = threadIdx.x;
    const int bid  = blockIdx.x;
    const int w    = tid >> 6;        // wave 0..7 -> hf {2w, 2w+1}
    const int lane = tid & 63;
    const int lh   = lane & 15;
    const int kq   = lane >> 4;       // 0..3
    const int b0   = bid * 2;

    // ---- init state (rows r = bl*32 + p  <->  global row p*64 + b0+bl)
    for (int s = tid; s < 16384; s += 512) {
        int r = s >> 8, k = s & 255;
        int bl = r >> 5, p = r & 31;
        size_t grow = ((size_t)p * 64 + b0 + bl) * 256 + k;
        float v = h0[grow];
        unsigned short uh = bfh(v);
        hhS[r * 264 + k] = uh;
        hlS[r * 264 + k] = bfh(v - bff(uh));
        cS [r * 264 + k] = c0[grow];
    }
    if (tid < 64) idxS[tid >> 5][tid & 31] = tid & 31;
    float pb_reg = -3.4657359027997265f;   // waves 0,1 lanes<32: per-(b,p) state

    // ---- step-invariant constants
    const int hcA = (2 * w) * 16 + lh;
    const int hcB = hcA + 16;
    float bsum[5][2];
    #pragma unroll
    for (int g = 0; g < 5; ++g) {
        bsum[g][0] = b_ih[g * 256 + hcA] + b_hh[g * 256 + hcA];
        bsum[g][1] = b_ih[g * 256 + hcB] + b_hh[g * 256 + hcB];
    }
    const float wobs0 = W_obs[hcA], wobs1 = W_obs[hcB];
    const float wlab0 = W_lab[hcA], wlab1 = W_lab[hcB];
    const float blab  = b_lab[0];
    const short8* bw = (const short8*)Bpk2 + (size_t)w * 10240;

    __syncthreads();

    #pragma unroll 1
    for (int t = 0; t < TT; ++t) {
        // ---- stage gumbel tiles (2 x 4KB)
        {
            int bl = tid >> 8, q = tid & 255;
            f4 v = ((const f4*)(gumG + (size_t)t * 65536 +
                                (size_t)(b0 + bl) * 1024))[q];
            int p = q >> 3, j0 = (q & 7) * 4;
            gumS[bl][p][j0 + 0] = v.x; gumS[bl][p][j0 + 1] = v.y;
            gumS[bl][p][j0 + 2] = v.z; gumS[bl][p][j0 + 3] = v.w;
        }
        // ---- ancestor rows + eps prefetch
        int rowA[4];
        #pragma unroll
        for (int fr = 0; fr < 4; ++fr)
            rowA[fr] = (fr >> 1) * 32 + idxS[fr >> 1][(fr & 1) * 16 + lh];
        float epre[4][2][4];
        #pragma unroll
        for (int fr = 0; fr < 4; ++fr)
            #pragma unroll
            for (int reg = 0; reg < 4; ++reg) {
                int p = (fr & 1) * 16 + kq * 4 + reg;
                const float* ep = eps + ((size_t)t * 2048 +
                    (size_t)p * 64 + b0 + (fr >> 1)) * 256;
                epre[fr][0][reg] = ep[hcA];
                epre[fr][1][reg] = ep[hcB];
            }

        // ---- GEMM: acc[fr][cf], cf = ha*5+g
        f32x4 acc[4][10];
        #pragma unroll
        for (int fr = 0; fr < 4; ++fr)
            #pragma unroll
            for (int cf = 0; cf < 10; ++cf) acc[fr][cf] = (f32x4)(0.0f);

        #pragma unroll
        for (int cs = 0; cs < 8; ++cs) {
            short8 Ah[4], Al[4];
            #pragma unroll
            for (int fr = 0; fr < 4; ++fr) {
                Ah[fr] = *(const short8*)&hhS[rowA[fr] * 264 + cs * 32 + kq * 8];
                Al[fr] = *(const short8*)&hlS[rowA[fr] * 264 + cs * 32 + kq * 8];
            }
            const short8* bcs = bw + cs * 1280;
            #pragma unroll
            for (int cf = 0; cf < 10; ++cf) {
                short8 Bh = bcs[cf * 128 + lane];
                short8 Bl = bcs[cf * 128 + 64 + lane];
                #pragma unroll
                for (int fr = 0; fr < 4; ++fr) {
                    // per-acc order: Ah*Bh, Ah*Bl, Al*Bh (round-10 lineage)
                    acc[fr][cf] = __builtin_amdgcn_mfma_f32_16x16x32_bf16(Ah[fr], Bh, acc[fr][cf], 0, 0, 0);
                    acc[fr][cf] = __builtin_amdgcn_mfma_f32_16x16x32_bf16(Ah[fr], Bl, acc[fr][cf], 0, 0, 0);
                    acc[fr][cf] = __builtin_amdgcn_mfma_f32_16x16x32_bf16(Al[fr], Bh, acc[fr][cf], 0, 0, 0);
                }
            }
        }
        __syncthreads();   // all gathered h/c LDS reads of the GEMM complete

        // ---- gather c (LDS) + embW before the state is overwritten
        float cpre[4][2][4];
        #pragma unroll
        for (int fr = 0; fr < 4; ++fr)
            #pragma unroll
            for (int reg = 0; reg < 4; ++reg) {
                int p  = (fr & 1) * 16 + kq * 4 + reg;
                int ar = (fr >> 1) * 32 + idxS[fr >> 1][p];
                cpre[fr][0][reg] = cS[ar * 264 + hcA];
                cpre[fr][1][reg] = cS[ar * 264 + hcB];
            }
        float ew[2][2][5];
        #pragma unroll
        for (int bl = 0; bl < 2; ++bl) {
            const float* ewp = embW2 + ((size_t)t * 64 + b0 + bl) * 1280;
            #pragma unroll
            for (int g = 0; g < 5; ++g) {
                ew[bl][0][g] = ewp[g * 256 + hcA];
                ew[bl][1][g] = ewp[g * 256 + hcB];
            }
        }
        __syncthreads();   // cpre reads complete before epilogue writes

        // ---- epilogue: LSTM + state writes + dot partials
        float po[4][4], pl[4][4];
        #pragma unroll
        for (int fr = 0; fr < 4; ++fr)
            #pragma unroll
            for (int reg = 0; reg < 4; ++reg) { po[fr][reg] = 0.0f; pl[fr][reg] = 0.0f; }

        #pragma unroll
        for (int fr = 0; fr < 4; ++fr) {
            int bl = fr >> 1;
            #pragma unroll
            for (int ha = 0; ha < 2; ++ha) {
                int hc = ha ? hcB : hcA;
                float wo = ha ? wobs1 : wobs0;
                float wl = ha ? wlab1 : wlab0;
                #pragma unroll
                for (int reg = 0; reg < 4; ++reg) {
                    int p   = (fr & 1) * 16 + kq * 4 + reg;
                    int row = bl * 32 + p;
                    float gi = acc[fr][ha * 5 + 0][reg] + bsum[0][ha] + ew[bl][ha][0];
                    float gf = acc[fr][ha * 5 + 1][reg] + bsum[1][ha] + ew[bl][ha][1];
                    float gg = acc[fr][ha * 5 + 2][reg] + bsum[2][ha] + ew[bl][ha][2];
                    float go = acc[fr][ha * 5 + 3][reg] + bsum[3][ha] + ew[bl][ha][3];
                    float gv = acc[fr][ha * 5 + 4][reg] + bsum[4][ha] + ew[bl][ha][4];

                    float mu  = sigm(gf) * cpre[fr][ha][reg] + sigm(gi) * tanhf(gg);
                    float c1v = mu + splus(gv) * epre[fr][ha][reg];
                    float h1v = sigm(go) * tanhf(c1v);

                    cS[row * 264 + hc] = c1v;
                    unsigned short uh = bfh(h1v);
                    hhS[row * 264 + hc] = uh;
                    hlS[row * 264 + hc] = bfh(h1v - bff(uh));

                    po[fr][reg] += h1v * wo;
                    pl[fr][reg] += h1v * wl;
                }
            }
        }
        #pragma unroll
        for (int fr = 0; fr < 4; ++fr)
            #pragma unroll
            for (int reg = 0; reg < 4; ++reg) {
                float s = po[fr][reg];
                s += __shfl_xor(s, 1); s += __shfl_xor(s, 2);
                s += __shfl_xor(s, 4); s += __shfl_xor(s, 8);
                float s2 = pl[fr][reg];
                s2 += __shfl_xor(s2, 1); s2 += __shfl_xor(s2, 2);
                s2 += __shfl_xor(s2, 4); s2 += __shfl_xor(s2, 8);
                if (lh == 0) {
                    int row = (fr >> 1) * 32 + (fr & 1) * 16 + kq * 4 + reg;
                    wdp[w][row][0] = s;
                    wdp[w][row][1] = s2;
                }
            }
        __syncthreads();   // wdp + state visible

        // ---- block-local resample: wave 0 -> b0, wave 1 -> b0+1
        if (w < 2 && lane < 32) {
            int bl = w, p = lane, bg = b0 + bl;
            float so = 0.0f, sl = 0.0f;
            #pragma unroll
            for (int ww = 0; ww < 8; ++ww) {
                so += wdp[ww][bl * 32 + p][0];
                sl += wdp[ww][bl * 32 + p][1];
            }
            float v = pb_reg + so + xobs[t * 64 + bg];
            float m = v;
            #pragma unroll
            for (int d = 1; d < 32; d <<= 1) m = fmaxf(m, __shfl_xor(m, d));
            float e = expf(v - m), se = e;
            #pragma unroll
            for (int d = 1; d < 32; d <<= 1) se += __shfl_xor(se, d);
            float w1  = expf(v - m - logf(se));
            float lgt = logf(0.5f * w1 + 0.015625f);

            float best = -INFINITY; int bi = 0;
            #pragma unroll
            for (int j = 0; j < 32; ++j) {
                float val = __shfl(lgt, j) + gumS[bl][p][j];
                if (val > best) { best = val; bi = j; }   // first max
            }
            idxS[bl][p] = bi;

            float wv = __shfl(w1, bi);
            wv = wv / (0.5f * wv + 0.015625f);
            float lw = logf(wv);
            float m2 = lw;
            #pragma unroll
            for (int d = 1; d < 32; d <<= 1) m2 = fmaxf(m2, __shfl_xor(m2, d));
            float e2 = expf(lw - m2), ss = e2;
            #pragma unroll
            for (int d = 1; d < 32; d <<= 1) ss += __shfl_xor(ss, d);
            float pn = lw - m2 - logf(ss);
            pb_reg = pn;

            float dd = __shfl(sl, bi);
            pf_out[(size_t)t * 2048 + p * 64 + bg] =
                1.0f / (1.0f + expf(-(dd + blab)));
            float contrib = expf(pn) * dd;
            #pragma unroll
            for (int d = 1; d < 32; d <<= 1) contrib += __shfl_xor(contrib, d);
            if (p == 0)
                y_out[t * 64 + bg] = 1.0f / (1.0f + expf(-(contrib + blab)));
        }
        __syncthreads();   // idxS ready for next step
    }
}

// ---------------------------------------------------------------------------
extern "C" void kernel_launch(void* const* d_in, const int* in_sizes, int n_in,
                              void* d_out, int out_size, void* d_ws, size_t ws_size,
                              hipStream_t stream)
{
    const float* prev_window = (const float*)d_in[0];
    const float* h0    = (const float*)d_in[1];
    const float* c0    = (const float*)d_in[2];
    const float* eps   = (const float*)d_in[3];
    const float* gum   = (const float*)d_in[4];
    const float* W_act = (const float*)d_in[5];
    const float* b_act = (const float*)d_in[6];
    const float* W_ih  = (const float*)d_in[7];
    const float* b_ih  = (const float*)d_in[8];
    const float* W_hh  = (const float*)d_in[9];
    const float* b_hh  = (const float*)d_in[10];
    const float* W_obs = (const float*)d_in[11];
    const float* b_obs = (const float*)d_in[12];
    const float* W_lab = (const float*)d_in[13];
    const float* b_lab = (const float*)d_in[14];

    float* out = (float*)d_out;           // [T*B] y_out, then [T*P*B] pf_out
    char* w = (char*)d_ws;

    unsigned short* Bpk2 = (unsigned short*)(w);            // 1,310,720 B
    float* emb   = (float*)(w + 1310720);                   // 1,638,400 B
    float* embW2 = (float*)(w + 2949120);                   // 32,768,000 B
    float* xobs  = (float*)(w + 35717120);                  //    25,600 B

    k_emb<<<1600, 256, 0, stream>>>(prev_window, W_act, b_act, W_obs, b_obs,
                                    emb, xobs);
    k_embW<<<1600, 256, 0, stream>>>(emb, W_ih, embW2);
    k_packB2<<<2560, 256, 0, stream>>>(W_hh, Bpk2);

    pf_all<<<32, 512, 0, stream>>>(
        Bpk2, embW2, h0, c0, eps, gum, xobs,
        b_ih, b_hh, W_obs, W_lab, b_lab,
        out, out + TT * BB);
}

// Round 16
// 2447.354 us; speedup vs baseline: 4.9418x; 4.9418x over previous
//
#include <hip/hip_runtime.h>
#include <hip/hip_bf16.h>
#include <cstddef>
#include <cstdint>

#define PP 32
#define BB 64
#define TT 100
#define WW 50
#define EE 64
#define HH 256
// ALPHA = 0.5, (1-ALPHA)/P = 0.015625

typedef float f4 __attribute__((ext_vector_type(4)));
typedef __attribute__((ext_vector_type(8))) short short8;   // 8 bf16 (4 VGPRs)
typedef __attribute__((ext_vector_type(4))) float f32x4;

__device__ __forceinline__ float sigm(float x) { return 1.0f / (1.0f + expf(-x)); }
__device__ __forceinline__ float splus(float x) {
    return fmaxf(x, 0.0f) + log1pf(expf(-fabsf(x)));
}
__device__ __forceinline__ unsigned short bfh(float x) {
    __hip_bfloat16 h = __float2bfloat16(x);           // RNE
    return *reinterpret_cast<unsigned short*>(&h);
}
__device__ __forceinline__ float bff(unsigned short u) {
    __hip_bfloat16 h; *reinterpret_cast<unsigned short*>(&h) = u;
    return __bfloat162float(h);
}

// ---------------------------------------------------------------------------
// Prologue A: emb = relu(prev_window @ W_act + b_act) -> bf16 hi/lo split
// [t][b][e]; xobs[t*64+b] = emb . W_obs[256:320] + b_obs (fp32 exact path)
// ---------------------------------------------------------------------------
__global__ __launch_bounds__(256) void k_emb(
    const float* __restrict__ pw, const float* __restrict__ w_act,
    const float* __restrict__ b_act, const float* __restrict__ w_obs,
    const float* __restrict__ b_obs,
    unsigned short* __restrict__ embh, unsigned short* __restrict__ embl,
    float* __restrict__ xobs)
{
    int tid = threadIdx.x;
    int sub = tid >> 6;
    int e   = tid & 63;
    int bt  = blockIdx.x * 4 + sub;   // = b*100 + t
    int b = bt / TT, t = bt % TT;

    __shared__ float pws[4][WW + 2];
    if (e < WW) pws[sub][e] = pw[(size_t)bt * WW + e];
    __syncthreads();

    float acc = b_act[e];
    #pragma unroll 5
    for (int w = 0; w < WW; ++w) acc += pws[sub][w] * w_act[w * EE + e];
    float r = fmaxf(acc, 0.0f);

    unsigned short uh = bfh(r);
    embh[((size_t)t * BB + b) * EE + e] = uh;
    embl[((size_t)t * BB + b) * EE + e] = bfh(r - bff(uh));

    float xv = r * w_obs[HH + e];
    #pragma unroll
    for (int d = 1; d < 64; d <<= 1) xv += __shfl_xor(xv, d);
    if (e == 0) xobs[t * BB + b] = xv + b_obs[0];
}

// ---------------------------------------------------------------------------
// Prologue B: pack weights into MFMA-fragment order, bf16 hi/lo.
// Layout: [colp 16][bidx 20][g 5][lane 64][e 8] (ushort).
//   bidx 0..9 hi (k = bidx*32 + (lane>>4)*8 + e), 10..19 lo.
//   col = g*256 + colp*16 + (lane&15); k<256 from W_hh, else W_ih.
// ---------------------------------------------------------------------------
__global__ __launch_bounds__(256) void k_packB(
    const float* __restrict__ W_ih, const float* __restrict__ W_hh,
    unsigned short* __restrict__ Bp)
{
    int i = blockIdx.x * 256 + threadIdx.x;    // 819200 total
    int colp = i / 51200;  int r = i - colp * 51200;
    int bidx = r / 2560;   r -= bidx * 2560;
    int g    = r / 512;    r -= g * 512;
    int lane = r >> 3;     int e = r & 7;

    int c = (bidx < 10) ? bidx : (bidx - 10);
    int k = c * 32 + (lane >> 4) * 8 + e;
    int col = g * HH + colp * 16 + (lane & 15);
    float w = (k < HH) ? W_hh[(size_t)k * 1280 + col]
                       : W_ih[(size_t)(k - HH) * 1280 + col];
    unsigned short uh = bfh(w);
    Bp[i] = (bidx < 10) ? uh : bfh(w - bff(uh));
}

// ---------------------------------------------------------------------------
// Prologue C: split h0 into bf16 hi/lo (into parity-A h buffers); copy c0.
// ---------------------------------------------------------------------------
__global__ __launch_bounds__(256) void k_split0(
    const float* __restrict__ h0, const float* __restrict__ c0,
    unsigned short* __restrict__ hh, unsigned short* __restrict__ hl,
    float* __restrict__ cc)
{
    int i = blockIdx.x * 256 + threadIdx.x;    // 524288
    float v = h0[i];
    unsigned short uh = bfh(v);
    hh[i] = uh;
    hl[i] = bfh(v - bff(uh));
    cc[i] = c0[i];
}

// ---------------------------------------------------------------------------
// S1: MFMA GEMM + LSTM elementwise + partial output dots.  Per step.
// grid 512 x 256 thr (4 waves, 2 blk/CU).
// Block swizzle accounts for the XCD round-robin: cp = (bid>>4)&15 so that
// blocks i and i+256 (which co-reside on one CU) share the SAME cp ->
// shared Bh slab + Bl lines in L1.  rp = ((bid>>8)<<4)|(bid&15).
// Bh (50 KB) staged in LDS; Bl + A direct from global.
// Epilogue inputs (gidx/c_in/eps) hoisted above the K-loop so their
// latency hides under the 150 MFMAs.
// Single-pass K: per slice cs (0..9) load Ah,Al + Bh[5](LDS),Bl[5](global),
// issue 15 MFMAs (Ah*Bh, Ah*Bl, Al*Bh per gate).  K_eff = 960.
// ---------------------------------------------------------------------------
__global__ __launch_bounds__(256, 2) void s1_mfma(
    const unsigned short* __restrict__ Bp,
    const unsigned short* __restrict__ embh_t, const unsigned short* __restrict__ embl_t,
    const unsigned short* __restrict__ hh_in, const unsigned short* __restrict__ hl_in,
    const float* __restrict__ c_in,
    unsigned short* __restrict__ hh_out, unsigned short* __restrict__ hl_out,
    float* __restrict__ c_out,
    const int* __restrict__ gidx,            // null at t=0 (identity)
    const float* __restrict__ b_ih, const float* __restrict__ b_hh,
    const float* __restrict__ w_obs, const float* __restrict__ w_lab,
    const float* __restrict__ eps_t,
    float* __restrict__ dpo, float* __restrict__ dpl)   // [16][2048] each
{
    __shared__ short8 BhL[3200];        // [cs 10][g 5][lane 64] = 50 KB

    const int tid  = threadIdx.x;
    const int cp   = (blockIdx.x >> 4) & 15;                    // CU-pair shared
    const int rp   = ((blockIdx.x >> 8) << 4) | (blockIdx.x & 15);  // 0..31
    const int lane = tid & 63;
    const int w    = tid >> 6;          // wave 0..3
    const int lh   = lane & 15;
    const int kq   = lane >> 4;         // 0..3
    const int R0   = rp * 64 + w * 16;

    // ---- stage Bh chunks (bidx 0..9) into LDS, linear copy from L2-hot Bp
    {
        const short8* src = (const short8*)Bp + (size_t)cp * 6400;
        for (int s = tid; s < 3200; s += 256) BhL[s] = src[s];
    }

    // ---- A-frag base addresses (gather-on-read via gidx)
    const int myrow = R0 + lh;
    const int sr    = gidx ? gidx[myrow] : myrow;
    const size_t hoff = (size_t)sr * 512 + (size_t)kq * 16;            // bytes
    const size_t eoff = (size_t)(myrow & 63) * 128 + (size_t)kq * 16;  // bytes

    // ---- hoist epilogue inputs (c_in gather + eps) above the K-loop
    const int hcol = cp * 16 + lh;
    float cpre[4], epre[4];
    #pragma unroll
    for (int reg = 0; reg < 4; ++reg) {
        int row = R0 + kq * 4 + reg;
        int sr2 = gidx ? gidx[row] : row;
        cpre[reg] = c_in[(size_t)sr2 * HH + hcol];
        epre[reg] = eps_t[(size_t)row * HH + hcol];
    }

    f32x4 acc[5];
    #pragma unroll
    for (int g = 0; g < 5; ++g) acc[g] = (f32x4)(0.0f);

    const char* hhp = (const char*)hh_in  + hoff;
    const char* hlp = (const char*)hl_in  + hoff;
    const char* ehp = (const char*)embh_t + eoff;
    const char* elp = (const char*)embl_t + eoff;
    const short8* bslab = (const short8*)Bp + (size_t)cp * 6400 + lane;
    // Bl frag (cs,g): bslab[((cs+10)*5+g)*64]

    __syncthreads();   // BhL ready

    #pragma unroll
    for (int cs = 0; cs < 10; ++cs) {
        short8 Ah, Al;
        if (cs < 8) {
            Ah = *(const short8*)(hhp + cs * 64);
            Al = *(const short8*)(hlp + cs * 64);
        } else {
            Ah = *(const short8*)(ehp + (cs - 8) * 64);
            Al = *(const short8*)(elp + (cs - 8) * 64);
        }
        short8 Bh[5], Bl[5];
        #pragma unroll
        for (int g = 0; g < 5; ++g) {
            Bh[g] = BhL[(cs * 5 + g) * 64 + lane];
            Bl[g] = bslab[((cs + 10) * 5 + g) * 64];
        }
        // per-acc order: Ah*Bh, Ah*Bl, Al*Bh
        #pragma unroll
        for (int g = 0; g < 5; ++g)
            acc[g] = __builtin_amdgcn_mfma_f32_16x16x32_bf16(Ah, Bh[g], acc[g], 0, 0, 0);
        #pragma unroll
        for (int g = 0; g < 5; ++g)
            acc[g] = __builtin_amdgcn_mfma_f32_16x16x32_bf16(Ah, Bl[g], acc[g], 0, 0, 0);
        #pragma unroll
        for (int g = 0; g < 5; ++g)
            acc[g] = __builtin_amdgcn_mfma_f32_16x16x32_bf16(Al, Bh[g], acc[g], 0, 0, 0);
    }

    // ---- epilogue (C-layout: col = lane&15, row = (lane>>4)*4 + reg)
    float bsum[5];
    #pragma unroll
    for (int g = 0; g < 5; ++g) bsum[g] = b_ih[g * HH + hcol] + b_hh[g * HH + hcol];
    const float wobs_l = w_obs[hcol];
    const float wlab_l = w_lab[hcol];

    #pragma unroll
    for (int reg = 0; reg < 4; ++reg) {
        int row = R0 + kq * 4 + reg;

        float gi = acc[0][reg] + bsum[0];
        float gf = acc[1][reg] + bsum[1];
        float gg = acc[2][reg] + bsum[2];
        float go = acc[3][reg] + bsum[3];
        float gv = acc[4][reg] + bsum[4];

        float mu  = sigm(gf) * cpre[reg] + sigm(gi) * tanhf(gg);
        float c1v = mu + splus(gv) * epre[reg];
        float h1v = sigm(go) * tanhf(c1v);

        c_out[(size_t)row * HH + hcol] = c1v;
        unsigned short uh = bfh(h1v);
        hh_out[(size_t)row * HH + hcol] = uh;
        hl_out[(size_t)row * HH + hcol] = bfh(h1v - bff(uh));

        float po = h1v * wobs_l, pl = h1v * wlab_l;
        po += __shfl_xor(po, 1); po += __shfl_xor(po, 2);
        po += __shfl_xor(po, 4); po += __shfl_xor(po, 8);
        pl += __shfl_xor(pl, 1); pl += __shfl_xor(pl, 2);
        pl += __shfl_xor(pl, 4); pl += __shfl_xor(pl, 8);
        if (lh == 0) {
            dpo[cp * 2048 + row] = po;
            dpl[cp * 2048 + row] = pl;
        }
    }
}

// ---------------------------------------------------------------------------
// S2: per batch-column b (64 blocks x 256 thr): reduce 16 partial dots,
// log-softmax over P, gumbel-argmax, write gidx, emit pf_out and y_out.
// ---------------------------------------------------------------------------
__global__ __launch_bounds__(256) void s2_kernel(
    const float* __restrict__ dpo, const float* __restrict__ dpl,
    const float* __restrict__ xobs_t, const float* __restrict__ g_t,
    const float* __restrict__ b_lab,
    float* __restrict__ p_buf, int first,
    int* __restrict__ gidx_next,
    float* __restrict__ y_out_t, float* __restrict__ pf_out_t)
{
    int b   = blockIdx.x;
    int tid = threadIdx.x;

    __shared__ float gt[PP][PP + 1];
    __shared__ float lg[PP];
    __shared__ float w1s[PP];
    __shared__ float lgt[PP];
    __shared__ float pnew[PP];
    __shared__ float dpart[PP];
    __shared__ int   idxs[PP];

    // stage gumbel tile (32x32), 256 threads x 1 float4
    {
        f4 v = ((const f4*)(g_t + (size_t)b * 1024))[tid];
        int p = tid >> 3, j0 = (tid & 7) * 4;
        gt[p][j0 + 0] = v.x; gt[p][j0 + 1] = v.y;
        gt[p][j0 + 2] = v.z; gt[p][j0 + 3] = v.w;
    }

    int p = tid >> 3, j = tid & 7;
    // reduce 16 dpo partials: thread (p, j) takes ct = j and j+8
    {
        int o = p * BB + b;
        float s = dpo[j * 2048 + o] + dpo[(j + 8) * 2048 + o];
        s += __shfl_xor(s, 1); s += __shfl_xor(s, 2); s += __shfl_xor(s, 4);
        if (j == 0) {
            float pprev = first ? -3.4657359027997265f : p_buf[o];
            lg[p] = pprev + s + xobs_t[b];
        }
    }
    __syncthreads();

    // log-softmax over P; w1; logits
    if (tid < 32) {
        float v = lg[tid];
        float m = v;
        #pragma unroll
        for (int d = 1; d < 32; d <<= 1) m = fmaxf(m, __shfl_xor(m, d));
        float e = expf(v - m), se = e;
        #pragma unroll
        for (int d = 1; d < 32; d <<= 1) se += __shfl_xor(se, d);
        float l1 = v - m - logf(se);
        float w1 = expf(l1);
        w1s[tid] = w1;
        lgt[tid] = logf(0.5f * w1 + 0.015625f);
    }
    __syncthreads();

    // gumbel-argmax resample; new weights; p_new
    if (tid < 32) {
        int p2 = tid;
        float best = -INFINITY; int bi = 0;
        #pragma unroll 8
        for (int jj = 0; jj < 32; ++jj) {
            float val = lgt[jj] + gt[p2][jj];
            if (val > best) { best = val; bi = jj; }   // first max, like jnp.argmax
        }
        idxs[p2] = bi;
        gidx_next[p2 * BB + b] = bi * BB + b;

        float wv = w1s[bi];
        wv = wv / (0.5f * wv + 0.015625f);
        float lw = logf(wv);
        float m2 = lw;
        #pragma unroll
        for (int d = 1; d < 32; d <<= 1) m2 = fmaxf(m2, __shfl_xor(m2, d));
        float e2 = expf(lw - m2), s2 = e2;
        #pragma unroll
        for (int d = 1; d < 32; d <<= 1) s2 += __shfl_xor(s2, d);
        float pn = lw - m2 - logf(s2);
        pnew[p2] = pn;
        p_buf[p2 * BB + b] = pn;
    }
    __syncthreads();

    // reduce 16 dpl partials at resampled rows
    {
        int src = idxs[p] * BB + b;
        float d = dpl[j * 2048 + src] + dpl[(j + 8) * 2048 + src];
        d += __shfl_xor(d, 1); d += __shfl_xor(d, 2); d += __shfl_xor(d, 4);
        if (j == 0) dpart[p] = d;
    }
    __syncthreads();

    if (tid < 32) {
        float dd = dpart[tid];
        float bl = b_lab[0];
        pf_out_t[tid * BB + b] = 1.0f / (1.0f + expf(-(dd + bl)));
        float contrib = expf(pnew[tid]) * dd;
        #pragma unroll
        for (int d = 1; d < 32; d <<= 1) contrib += __shfl_xor(contrib, d);
        if (tid == 0) y_out_t[b] = 1.0f / (1.0f + expf(-(contrib + bl)));
    }
}

// ---------------------------------------------------------------------------
extern "C" void kernel_launch(void* const* d_in, const int* in_sizes, int n_in,
                              void* d_out, int out_size, void* d_ws, size_t ws_size,
                              hipStream_t stream)
{
    const float* prev_window = (const float*)d_in[0];
    const float* h0    = (const float*)d_in[1];
    const float* c0    = (const float*)d_in[2];
    const float* eps   = (const float*)d_in[3];
    const float* gum   = (const float*)d_in[4];
    const float* W_act = (const float*)d_in[5];
    const float* b_act = (const float*)d_in[6];
    const float* W_ih  = (const float*)d_in[7];
    const float* b_ih  = (const float*)d_in[8];
    const float* W_hh  = (const float*)d_in[9];
    const float* b_hh  = (const float*)d_in[10];
    const float* W_obs = (const float*)d_in[11];
    const float* b_obs = (const float*)d_in[12];
    const float* W_lab = (const float*)d_in[13];
    const float* b_lab = (const float*)d_in[14];

    float* out = (float*)d_out;           // [T*B] y_out, then [T*P*B] pf_out
    char* w = (char*)d_ws;

    unsigned short* Bp   = (unsigned short*)(w);               // 1,638,400 B
    unsigned short* embh = (unsigned short*)(w + 1638400);     //   819,200
    unsigned short* embl = (unsigned short*)(w + 2457600);     //   819,200
    unsigned short* hhA  = (unsigned short*)(w + 3276800);     // 1,048,576
    unsigned short* hlA  = (unsigned short*)(w + 4325376);
    unsigned short* hhB  = (unsigned short*)(w + 5373952);
    unsigned short* hlB  = (unsigned short*)(w + 6422528);
    float*  cA   = (float*)(w + 7471104);                      // 2,097,152
    float*  cB   = (float*)(w + 9568256);
    float*  xobs = (float*)(w + 11665408);                     //    25,600
    float*  pbuf = (float*)(w + 11691008);
    int*    gidx = (int*)(w + 11699200);
    float*  dpo  = (float*)(w + 11707392);                     //   131,072
    float*  dpl  = (float*)(w + 11838464);

    k_emb<<<1600, 256, 0, stream>>>(prev_window, W_act, b_act, W_obs, b_obs,
                                    embh, embl, xobs);
    k_packB<<<3200, 256, 0, stream>>>(W_ih, W_hh, Bp);
    k_split0<<<2048, 256, 0, stream>>>(h0, c0, hhA, hlA, cA);

    for (int t = 0; t < TT; ++t) {
        const unsigned short* hh_in = (t & 1) ? hhB : hhA;
        const unsigned short* hl_in = (t & 1) ? hlB : hlA;
        const float*          c_in  = (t & 1) ? cB  : cA;
        unsigned short* hh_out = (t & 1) ? hhA : hhB;
        unsigned short* hl_out = (t & 1) ? hlA : hlB;
        float*          c_out  = (t & 1) ? cA  : cB;

        s1_mfma<<<512, 256, 0, stream>>>(
            Bp, embh + (size_t)t * 4096, embl + (size_t)t * 4096,
            hh_in, hl_in, c_in, hh_out, hl_out, c_out,
            (t == 0) ? nullptr : gidx,
            b_ih, b_hh, W_obs, W_lab,
            eps + (size_t)t * 524288,
            dpo, dpl);

        s2_kernel<<<64, 256, 0, stream>>>(
            dpo, dpl, xobs + t * BB, gum + (size_t)t * 65536,
            b_lab, pbuf, (t == 0) ? 1 : 0, gidx,
            out + (size_t)t * BB,
            out + (size_t)TT * BB + (size_t)t * PP * BB);
    }
}

// Round 17
// 2404.354 us; speedup vs baseline: 5.0302x; 1.0179x over previous
//
#include <hip/hip_runtime.h>
#include <hip/hip_bf16.h>
#include <cstddef>
#include <cstdint>

#define PP 32
#define BB 64
#define TT 100
#define WW 50
#define EE 64
#define HH 256
// ALPHA = 0.5, (1-ALPHA)/P = 0.015625

typedef float f4 __attribute__((ext_vector_type(4)));
typedef __attribute__((ext_vector_type(8))) short short8;   // 8 bf16 (4 VGPRs)
typedef __attribute__((ext_vector_type(4))) float f32x4;

__device__ __forceinline__ float sigm(float x) { return 1.0f / (1.0f + expf(-x)); }
__device__ __forceinline__ float splus(float x) {
    return fmaxf(x, 0.0f) + log1pf(expf(-fabsf(x)));
}
__device__ __forceinline__ unsigned short bfh(float x) {
    __hip_bfloat16 h = __float2bfloat16(x);           // RNE
    return *reinterpret_cast<unsigned short*>(&h);
}
__device__ __forceinline__ float bff(unsigned short u) {
    __hip_bfloat16 h; *reinterpret_cast<unsigned short*>(&h) = u;
    return __bfloat162float(h);
}

// ---------------------------------------------------------------------------
// Prologue A: emb = relu(prev_window @ W_act + b_act) -> bf16 hi/lo split
// [t][b][e]; xobs[t*64+b] = emb . W_obs[256:320] + b_obs (fp32 exact path)
// ---------------------------------------------------------------------------
__global__ __launch_bounds__(256) void k_emb(
    const float* __restrict__ pw, const float* __restrict__ w_act,
    const float* __restrict__ b_act, const float* __restrict__ w_obs,
    const float* __restrict__ b_obs,
    unsigned short* __restrict__ embh, unsigned short* __restrict__ embl,
    float* __restrict__ xobs)
{
    int tid = threadIdx.x;
    int sub = tid >> 6;
    int e   = tid & 63;
    int bt  = blockIdx.x * 4 + sub;   // = b*100 + t
    int b = bt / TT, t = bt % TT;

    __shared__ float pws[4][WW + 2];
    if (e < WW) pws[sub][e] = pw[(size_t)bt * WW + e];
    __syncthreads();

    float acc = b_act[e];
    #pragma unroll 5
    for (int w = 0; w < WW; ++w) acc += pws[sub][w] * w_act[w * EE + e];
    float r = fmaxf(acc, 0.0f);

    unsigned short uh = bfh(r);
    embh[((size_t)t * BB + b) * EE + e] = uh;
    embl[((size_t)t * BB + b) * EE + e] = bfh(r - bff(uh));

    float xv = r * w_obs[HH + e];
    #pragma unroll
    for (int d = 1; d < 64; d <<= 1) xv += __shfl_xor(xv, d);
    if (e == 0) xobs[t * BB + b] = xv + b_obs[0];
}

// ---------------------------------------------------------------------------
// Prologue B: pack weights into MFMA-fragment order, bf16 hi/lo.
// Layout: [colp 16][bidx 20][g 5][lane 64][e 8] (ushort).
//   bidx 0..9 hi (k = bidx*32 + (lane>>4)*8 + e), 10..19 lo.
//   col = g*256 + colp*16 + (lane&15); k<256 from W_hh, else W_ih.
// ---------------------------------------------------------------------------
__global__ __launch_bounds__(256) void k_packB(
    const float* __restrict__ W_ih, const float* __restrict__ W_hh,
    unsigned short* __restrict__ Bp)
{
    int i = blockIdx.x * 256 + threadIdx.x;    // 819200 total
    int colp = i / 51200;  int r = i - colp * 51200;
    int bidx = r / 2560;   r -= bidx * 2560;
    int g    = r / 512;    r -= g * 512;
    int lane = r >> 3;     int e = r & 7;

    int c = (bidx < 10) ? bidx : (bidx - 10);
    int k = c * 32 + (lane >> 4) * 8 + e;
    int col = g * HH + colp * 16 + (lane & 15);
    float w = (k < HH) ? W_hh[(size_t)k * 1280 + col]
                       : W_ih[(size_t)(k - HH) * 1280 + col];
    unsigned short uh = bfh(w);
    Bp[i] = (bidx < 10) ? uh : bfh(w - bff(uh));
}

// ---------------------------------------------------------------------------
// Prologue C: split h0 into bf16 hi/lo (into parity-A h buffers); copy c0.
// ---------------------------------------------------------------------------
__global__ __launch_bounds__(256) void k_split0(
    const float* __restrict__ h0, const float* __restrict__ c0,
    unsigned short* __restrict__ hh, unsigned short* __restrict__ hl,
    float* __restrict__ cc)
{
    int i = blockIdx.x * 256 + threadIdx.x;    // 524288
    float v = h0[i];
    unsigned short uh = bfh(v);
    hh[i] = uh;
    hl[i] = bfh(v - bff(uh));
    cc[i] = c0[i];
}

// ---------------------------------------------------------------------------
// S1: MFMA GEMM + LSTM elementwise + partial output dots.  Per step.
// grid 512 blocks = (cp = bid>>5, rp = bid&31) x 256 thr (4 waves, 2 blk/CU).
// Consecutive blocks share cp -> co-resident blocks share the B slab (L1).
// Bh (50 KB) staged in LDS (keeps 2 blocks/CU); Bl + A direct from global.
// Wave w owns rows rp*64 + w*16 .. +16 (one 16-row A frag) x 5 gate-frags.
// Single-pass K: per slice cs (0..9) load Ah,Al + Bh[5](LDS),Bl[5](global),
// issue 15 MFMAs (Ah*Bh, Ah*Bl, Al*Bh per gate).  K_eff = 960.
// ---------------------------------------------------------------------------
__global__ __launch_bounds__(256, 2) void s1_mfma(
    const unsigned short* __restrict__ Bp,
    const unsigned short* __restrict__ embh_t, const unsigned short* __restrict__ embl_t,
    const unsigned short* __restrict__ hh_in, const unsigned short* __restrict__ hl_in,
    const float* __restrict__ c_in,
    unsigned short* __restrict__ hh_out, unsigned short* __restrict__ hl_out,
    float* __restrict__ c_out,
    const int* __restrict__ gidx,            // null at t=0 (identity)
    const float* __restrict__ b_ih, const float* __restrict__ b_hh,
    const float* __restrict__ w_obs, const float* __restrict__ w_lab,
    const float* __restrict__ eps_t,
    float* __restrict__ dpo, float* __restrict__ dpl)   // [16][2048] each
{
    __shared__ short8 BhL[3200];        // [cs 10][g 5][lane 64] = 50 KB

    const int tid  = threadIdx.x;
    const int rp   = blockIdx.x & 31;   // consecutive blocks: same cp
    const int cp   = blockIdx.x >> 5;   // 0..15
    const int lane = tid & 63;
    const int w    = tid >> 6;          // wave 0..3
    const int lh   = lane & 15;
    const int kq   = lane >> 4;         // 0..3
    const int R0   = rp * 64 + w * 16;

    // ---- stage Bh chunks (bidx 0..9) into LDS, linear copy from L2-hot Bp
    {
        const short8* src = (const short8*)Bp + (size_t)cp * 6400;
        for (int s = tid; s < 3200; s += 256) BhL[s] = src[s];
    }

    // ---- A-frag base addresses (gather-on-read via gidx)
    const int myrow = R0 + lh;
    const int sr    = gidx ? gidx[myrow] : myrow;
    const size_t hoff = (size_t)sr * 512 + (size_t)kq * 16;            // bytes
    const size_t eoff = (size_t)(myrow & 63) * 128 + (size_t)kq * 16;  // bytes

    f32x4 acc[5];
    #pragma unroll
    for (int g = 0; g < 5; ++g) acc[g] = (f32x4)(0.0f);

    const char* hhp = (const char*)hh_in  + hoff;
    const char* hlp = (const char*)hl_in  + hoff;
    const char* ehp = (const char*)embh_t + eoff;
    const char* elp = (const char*)embl_t + eoff;
    const short8* bslab = (const short8*)Bp + (size_t)cp * 6400 + lane;
    // Bl frag (cs,g): bslab[((cs+10)*5+g)*64]

    __syncthreads();   // BhL ready

    #pragma unroll
    for (int cs = 0; cs < 10; ++cs) {
        short8 Ah, Al;
        if (cs < 8) {
            Ah = *(const short8*)(hhp + cs * 64);
            Al = *(const short8*)(hlp + cs * 64);
        } else {
            Ah = *(const short8*)(ehp + (cs - 8) * 64);
            Al = *(const short8*)(elp + (cs - 8) * 64);
        }
        short8 Bh[5], Bl[5];
        #pragma unroll
        for (int g = 0; g < 5; ++g) {
            Bh[g] = BhL[(cs * 5 + g) * 64 + lane];
            Bl[g] = bslab[((cs + 10) * 5 + g) * 64];
        }
        // per-acc order: Ah*Bh, Ah*Bl, Al*Bh
        #pragma unroll
        for (int g = 0; g < 5; ++g)
            acc[g] = __builtin_amdgcn_mfma_f32_16x16x32_bf16(Ah, Bh[g], acc[g], 0, 0, 0);
        #pragma unroll
        for (int g = 0; g < 5; ++g)
            acc[g] = __builtin_amdgcn_mfma_f32_16x16x32_bf16(Ah, Bl[g], acc[g], 0, 0, 0);
        #pragma unroll
        for (int g = 0; g < 5; ++g)
            acc[g] = __builtin_amdgcn_mfma_f32_16x16x32_bf16(Al, Bh[g], acc[g], 0, 0, 0);
    }

    // ---- epilogue (C-layout: col = lane&15, row = (lane>>4)*4 + reg)
    const int hcol = cp * 16 + lh;
    float bsum[5];
    #pragma unroll
    for (int g = 0; g < 5; ++g) bsum[g] = b_ih[g * HH + hcol] + b_hh[g * HH + hcol];
    const float wobs_l = w_obs[hcol];
    const float wlab_l = w_lab[hcol];

    #pragma unroll
    for (int reg = 0; reg < 4; ++reg) {
        int row = R0 + kq * 4 + reg;
        int sr2 = gidx ? gidx[row] : row;
        float cpv = c_in[(size_t)sr2 * HH + hcol];
        float ep  = eps_t[(size_t)row * HH + hcol];

        float gi = acc[0][reg] + bsum[0];
        float gf = acc[1][reg] + bsum[1];
        float gg = acc[2][reg] + bsum[2];
        float go = acc[3][reg] + bsum[3];
        float gv = acc[4][reg] + bsum[4];

        float mu  = sigm(gf) * cpv + sigm(gi) * tanhf(gg);
        float c1v = mu + splus(gv) * ep;
        float h1v = sigm(go) * tanhf(c1v);

        c_out[(size_t)row * HH + hcol] = c1v;
        unsigned short uh = bfh(h1v);
        hh_out[(size_t)row * HH + hcol] = uh;
        hl_out[(size_t)row * HH + hcol] = bfh(h1v - bff(uh));

        float po = h1v * wobs_l, pl = h1v * wlab_l;
        po += __shfl_xor(po, 1); po += __shfl_xor(po, 2);
        po += __shfl_xor(po, 4); po += __shfl_xor(po, 8);
        pl += __shfl_xor(pl, 1); pl += __shfl_xor(pl, 2);
        pl += __shfl_xor(pl, 4); pl += __shfl_xor(pl, 8);
        if (lh == 0) {
            dpo[cp * 2048 + row] = po;
            dpl[cp * 2048 + row] = pl;
        }
    }
}

// ---------------------------------------------------------------------------
// S2: per batch-column b (64 blocks x 256 thr): reduce 16 partial dots,
// log-softmax over P, gumbel-argmax, write gidx, emit pf_out and y_out.
// ---------------------------------------------------------------------------
__global__ __launch_bounds__(256) void s2_kernel(
    const float* __restrict__ dpo, const float* __restrict__ dpl,
    const float* __restrict__ xobs_t, const float* __restrict__ g_t,
    const float* __restrict__ b_lab,
    float* __restrict__ p_buf, int first,
    int* __restrict__ gidx_next,
    float* __restrict__ y_out_t, float* __restrict__ pf_out_t)
{
    int b   = blockIdx.x;
    int tid = threadIdx.x;

    __shared__ float gt[PP][PP + 1];
    __shared__ float lg[PP];
    __shared__ float w1s[PP];
    __shared__ float lgt[PP];
    __shared__ float pnew[PP];
    __shared__ float dpart[PP];
    __shared__ int   idxs[PP];

    // stage gumbel tile (32x32), 256 threads x 1 float4
    {
        f4 v = ((const f4*)(g_t + (size_t)b * 1024))[tid];
        int p = tid >> 3, j0 = (tid & 7) * 4;
        gt[p][j0 + 0] = v.x; gt[p][j0 + 1] = v.y;
        gt[p][j0 + 2] = v.z; gt[p][j0 + 3] = v.w;
    }

    int p = tid >> 3, j = tid & 7;
    // reduce 16 dpo partials: thread (p, j) takes ct = j and j+8
    {
        int o = p * BB + b;
        float s = dpo[j * 2048 + o] + dpo[(j + 8) * 2048 + o];
        s += __shfl_xor(s, 1); s += __shfl_xor(s, 2); s += __shfl_xor(s, 4);
        if (j == 0) {
            float pprev = first ? -3.4657359027997265f : p_buf[o];
            lg[p] = pprev + s + xobs_t[b];
        }
    }
    __syncthreads();

    // log-softmax over P; w1; logits
    if (tid < 32) {
        float v = lg[tid];
        float m = v;
        #pragma unroll
        for (int d = 1; d < 32; d <<= 1) m = fmaxf(m, __shfl_xor(m, d));
        float e = expf(v - m), se = e;
        #pragma unroll
        for (int d = 1; d < 32; d <<= 1) se += __shfl_xor(se, d);
        float l1 = v - m - logf(se);
        float w1 = expf(l1);
        w1s[tid] = w1;
        lgt[tid] = logf(0.5f * w1 + 0.015625f);
    }
    __syncthreads();

    // gumbel-argmax resample; new weights; p_new
    if (tid < 32) {
        int p2 = tid;
        float best = -INFINITY; int bi = 0;
        #pragma unroll 8
        for (int jj = 0; jj < 32; ++jj) {
            float val = lgt[jj] + gt[p2][jj];
            if (val > best) { best = val; bi = jj; }   // first max, like jnp.argmax
        }
        idxs[p2] = bi;
        gidx_next[p2 * BB + b] = bi * BB + b;

        float wv = w1s[bi];
        wv = wv / (0.5f * wv + 0.015625f);
        float lw = logf(wv);
        float m2 = lw;
        #pragma unroll
        for (int d = 1; d < 32; d <<= 1) m2 = fmaxf(m2, __shfl_xor(m2, d));
        float e2 = expf(lw - m2), s2 = e2;
        #pragma unroll
        for (int d = 1; d < 32; d <<= 1) s2 += __shfl_xor(s2, d);
        float pn = lw - m2 - logf(s2);
        pnew[p2] = pn;
        p_buf[p2 * BB + b] = pn;
    }
    __syncthreads();

    // reduce 16 dpl partials at resampled rows
    {
        int src = idxs[p] * BB + b;
        float d = dpl[j * 2048 + src] + dpl[(j + 8) * 2048 + src];
        d += __shfl_xor(d, 1); d += __shfl_xor(d, 2); d += __shfl_xor(d, 4);
        if (j == 0) dpart[p] = d;
    }
    __syncthreads();

    if (tid < 32) {
        float dd = dpart[tid];
        float bl = b_lab[0];
        pf_out_t[tid * BB + b] = 1.0f / (1.0f + expf(-(dd + bl)));
        float contrib = expf(pnew[tid]) * dd;
        #pragma unroll
        for (int d = 1; d < 32; d <<= 1) contrib += __shfl_xor(contrib, d);
        if (tid == 0) y_out_t[b] = 1.0f / (1.0f + expf(-(contrib + bl)));
    }
}

// ---------------------------------------------------------------------------
extern "C" void kernel_launch(void* const* d_in, const int* in_sizes, int n_in,
                              void* d_out, int out_size, void* d_ws, size_t ws_size,
                              hipStream_t stream)
{
    const float* prev_window = (const float*)d_in[0];
    const float* h0    = (const float*)d_in[1];
    const float* c0    = (const float*)d_in[2];
    const float* eps   = (const float*)d_in[3];
    const float* gum   = (const float*)d_in[4];
    const float* W_act = (const float*)d_in[5];
    const float* b_act = (const float*)d_in[6];
    const float* W_ih  = (const float*)d_in[7];
    const float* b_ih  = (const float*)d_in[8];
    const float* W_hh  = (const float*)d_in[9];
    const float* b_hh  = (const float*)d_in[10];
    const float* W_obs = (const float*)d_in[11];
    const float* b_obs = (const float*)d_in[12];
    const float* W_lab = (const float*)d_in[13];
    const float* b_lab = (const float*)d_in[14];

    float* out = (float*)d_out;           // [T*B] y_out, then [T*P*B] pf_out
    char* w = (char*)d_ws;

    unsigned short* Bp   = (unsigned short*)(w);               // 1,638,400 B
    unsigned short* embh = (unsigned short*)(w + 1638400);     //   819,200
    unsigned short* embl = (unsigned short*)(w + 2457600);     //   819,200
    unsigned short* hhA  = (unsigned short*)(w + 3276800);     // 1,048,576
    unsigned short* hlA  = (unsigned short*)(w + 4325376);
    unsigned short* hhB  = (unsigned short*)(w + 5373952);
    unsigned short* hlB  = (unsigned short*)(w + 6422528);
    float*  cA   = (float*)(w + 7471104);                      // 2,097,152
    float*  cB   = (float*)(w + 9568256);
    float*  xobs = (float*)(w + 11665408);                     //    25,600
    float*  pbuf = (float*)(w + 11691008);
    int*    gidx = (int*)(w + 11699200);
    float*  dpo  = (float*)(w + 11707392);                     //   131,072
    float*  dpl  = dpo + 32768;                                //   131,072

    k_emb<<<1600, 256, 0, stream>>>(prev_window, W_act, b_act, W_obs, b_obs,
                                    embh, embl, xobs);
    k_packB<<<3200, 256, 0, stream>>>(W_ih, W_hh, Bp);
    k_split0<<<2048, 256, 0, stream>>>(h0, c0, hhA, hlA, cA);

    for (int t = 0; t < TT; ++t) {
        const unsigned short* hh_in = (t & 1) ? hhB : hhA;
        const unsigned short* hl_in = (t & 1) ? hlB : hlA;
        const float*          c_in  = (t & 1) ? cB  : cA;
        unsigned short* hh_out = (t & 1) ? hhA : hhB;
        unsigned short* hl_out = (t & 1) ? hlA : hlB;
        float*          c_out  = (t & 1) ? cA  : cB;

        s1_mfma<<<512, 256, 0, stream>>>(
            Bp, embh + (size_t)t * 4096, embl + (size_t)t * 4096,
            hh_in, hl_in, c_in, hh_out, hl_out, c_out,
            (t == 0) ? nullptr : gidx,
            b_ih, b_hh, W_obs, W_lab,
            eps + (size_t)t * 524288,
            dpo, dpl);

        s2_kernel<<<64, 256, 0, stream>>>(
            dpo, dpl, xobs + t * BB, gum + (size_t)t * 65536,
            b_lab, pbuf, (t == 0) ? 1 : 0, gidx,
            out + (size_t)t * BB,
            out + (size_t)TT * BB + (size_t)t * PP * BB);
    }
}